// Round 2
// baseline (182359.692 us; speedup 1.0000x reference)
//
#include <hip/hip_runtime.h>
#include <cmath>

#define BATCHN 256
#define SEQT   1024
#define EMBED  1024
#define HID    1024
#define VOCABN 32000

typedef __attribute__((ext_vector_type(8))) _Float16 half8;
typedef __attribute__((ext_vector_type(4))) _Float16 half4;
typedef __attribute__((ext_vector_type(4))) float    float4v;

#define LOSCALE 4096.0f
#define LOINV   (1.0f/4096.0f)

__device__ inline void async16(const void* g, void* l) {
  __builtin_amdgcn_global_load_lds(
      (const __attribute__((address_space(1))) void*)g,
      (__attribute__((address_space(3))) void*)l, 16, 0, 0);
}

// ---------------- f32 -> f16 convert ----------------
__global__ void convert_f32_f16(const float* __restrict__ in,
                                _Float16* __restrict__ out, int n) {
  int i = (blockIdx.x * blockDim.x + threadIdx.x) * 4;
  if (i + 3 < n) {
    float4v v = *reinterpret_cast<const float4v*>(in + i);
    half4 o;
#pragma unroll
    for (int j = 0; j < 4; ++j) o[j] = (_Float16)v[j];
    *reinterpret_cast<half4*>(out + i) = o;
  }
}

// ---------------- f32 -> f16 hi/lo split (lo pre-scaled by 2^12) ----------------
__global__ void split_f32_f16(const float* __restrict__ in,
                              _Float16* __restrict__ hi,
                              _Float16* __restrict__ lo, int n) {
  int i = (blockIdx.x * blockDim.x + threadIdx.x) * 4;
  if (i + 3 < n) {
    float4v v = *reinterpret_cast<const float4v*>(in + i);
    half4 h, l;
#pragma unroll
    for (int j = 0; j < 4; ++j) {
      h[j] = (_Float16)v[j];
      l[j] = (_Float16)((v[j] - (float)h[j]) * LOSCALE);
    }
    *reinterpret_cast<half4*>(hi + i) = h;
    *reinterpret_cast<half4*>(lo + i) = l;
  }
}

// ---------------- Phase 1: xi = emb[x] @ Wi^T + bi  (f16 MFMA, 128x128 tile) ----------------
__global__ __launch_bounds__(256, 2) void gemm_xi(
    const _Float16* __restrict__ embh,  // [VOCAB][1024] f16
    const _Float16* __restrict__ Wih,   // [1024][1024] f16 (n-major, k inner)
    const int* __restrict__ x,          // [256][1024]
    const float* __restrict__ bi,       // [1024]
    _Float16* __restrict__ xi,          // [256*Tc][1024] f16
    int t0, int Tc)
{
  __shared__ __align__(16) _Float16 As[128 * 64];
  __shared__ __align__(16) _Float16 Bs[128 * 64];
  __shared__ int toks[128];

  const int tid  = threadIdx.x;
  const int wid  = tid >> 6, lane = tid & 63;
  const int nt   = blockIdx.x & 7, mt = blockIdx.x >> 3;
  const int m0   = mt * 128, n0 = nt * 128;

  if (tid < 128) {
    int m  = m0 + tid;
    int b  = m / Tc;          // Tc is a power of 2
    int tt = m - b * Tc;
    toks[tid] = x[b * SEQT + t0 + tt];
  }
  __syncthreads();

  const _Float16* aptr[4];
  const _Float16* bptr[4];
  int ldsoff[4];
#pragma unroll
  for (int i = 0; i < 4; ++i) {
    int idx = i * 256 + tid;
    int row = idx >> 3, kc = idx & 7;
    aptr[i]   = embh + (size_t)toks[row] * 1024 + kc * 8;
    bptr[i]   = Wih + ((size_t)(n0 + row) << 10) + kc * 8;
    ldsoff[i] = idx * 8;  // elements
  }

  float4v acc[4][4] = {};
  const int wm = wid & 1, wn = wid >> 1;
  const int cn = lane & 15, kg = lane >> 4;

  for (int k0 = 0; k0 < 1024; k0 += 64) {
#pragma unroll
    for (int i = 0; i < 4; ++i) {
      async16(aptr[i] + k0, &As[ldsoff[i]]);
      async16(bptr[i] + k0, &Bs[ldsoff[i]]);
    }
    __syncthreads();

    half8 a[4][2], b[4][2];
#pragma unroll
    for (int mf = 0; mf < 4; ++mf)
#pragma unroll
      for (int kf = 0; kf < 2; ++kf)
        a[mf][kf] = *reinterpret_cast<const half8*>(
            &As[(wm * 64 + mf * 16 + cn) * 64 + kf * 32 + kg * 8]);
#pragma unroll
    for (int nf = 0; nf < 4; ++nf)
#pragma unroll
      for (int kf = 0; kf < 2; ++kf)
        b[nf][kf] = *reinterpret_cast<const half8*>(
            &Bs[(wn * 64 + nf * 16 + cn) * 64 + kf * 32 + kg * 8]);

#pragma unroll
    for (int mf = 0; mf < 4; ++mf)
#pragma unroll
      for (int nf = 0; nf < 4; ++nf)
#pragma unroll
        for (int kf = 0; kf < 2; ++kf)
          acc[mf][nf] = __builtin_amdgcn_mfma_f32_16x16x32_f16(
              a[mf][kf], b[nf][kf], acc[mf][nf], 0, 0, 0);
    __syncthreads();
  }

  // epilogue: add bi, convert to f16, store
  const int r4 = kg * 4;
#pragma unroll
  for (int nf = 0; nf < 4; ++nf) {
    int n = n0 + wn * 64 + nf * 16 + cn;
    float biv = bi[n];
#pragma unroll
    for (int mf = 0; mf < 4; ++mf) {
      int mbase = m0 + wm * 64 + mf * 16 + r4;
#pragma unroll
      for (int j = 0; j < 4; ++j) {
        xi[((size_t)(mbase + j) << 10) + n] = (_Float16)(acc[mf][nf][j] + biv);
      }
    }
  }
}

// ---------------- Phase 2: sequential scan, 16 WGs x 16 batch rows ----------------
// Compensated product: a = hhi@Whi + LOINV*( (hlo*S)@Whi + hhi@(Wlo*S) )
__global__ __launch_bounds__(512, 2) void rnn_scan(
    const _Float16* __restrict__ Whi,   // [1024][1024] f16 (n-major)
    const _Float16* __restrict__ Wlo,   // [1024][1024] f16 residual * 2^12
    const float* __restrict__ bh,       // [1024]
    const _Float16* __restrict__ xi,    // [256*Tc][1024] f16
    float* __restrict__ hstate,         // [256][1024] f32
    float* __restrict__ out,            // [256][1024] f32
    int t0, int Tc)
{
  // h as f16 hi/lo pair, double-buffered. XOR swizzle: byte ^= (row&7)<<4
  __shared__ __align__(16) _Float16 Hhi[2][16 * 1024];
  __shared__ __align__(16) _Float16 Hlo[2][16 * 1024];

  const int tid  = threadIdx.x;
  const int wid  = tid >> 6, lane = tid & 63;
  const int r0   = blockIdx.x * 16;          // this WG's batch rows
  const int cn   = lane & 15, kg = lane >> 4;
  const int n0w  = wid * 128;                // this wave's 128 output cols

  // init buffer 0 (zeros at t0==0, else split hstate f32)
#pragma unroll
  for (int i = 0; i < 4; ++i) {
    int idx = i * 512 + tid;                 // 0..2047 8-elem chunks
    int row = idx >> 7, c = idx & 127;       // c: which 8-elem chunk in the row
    int byteoff = ((row << 11) + (c << 4)) ^ ((row & 7) << 4);
    half8 vh = (half8)(_Float16)0.0f, vl = (half8)(_Float16)0.0f;
    if (t0 != 0) {
      const float* hp = hstate + ((size_t)(r0 + row) << 10) + c * 8;
#pragma unroll
      for (int j = 0; j < 8; ++j) {
        float f = hp[j];
        _Float16 hi = (_Float16)f;
        vh[j] = hi;
        vl[j] = (_Float16)((f - (float)hi) * LOSCALE);
      }
    }
    *reinterpret_cast<half8*>(reinterpret_cast<char*>(&Hhi[0][0]) + byteoff) = vh;
    *reinterpret_cast<half8*>(reinterpret_cast<char*>(&Hlo[0][0]) + byteoff) = vl;
  }

  float bhv[8];
#pragma unroll
  for (int nf = 0; nf < 8; ++nf) bhv[nf] = bh[n0w + nf * 16 + cn];
  __syncthreads();

  for (int tt = 0; tt < Tc; ++tt) {
    const char* curh = reinterpret_cast<const char*>(&Hhi[tt & 1][0]);
    const char* curl = reinterpret_cast<const char*>(&Hlo[tt & 1][0]);
    char* nxth = reinterpret_cast<char*>(&Hhi[(tt + 1) & 1][0]);
    char* nxtl = reinterpret_cast<char*>(&Hlo[(tt + 1) & 1][0]);

    float4v acc1[8] = {};   // hhi @ Whi
    float4v acc2[8] = {};   // (hlo*S) @ Whi  +  hhi @ (Wlo*S)
#pragma unroll
    for (int kh = 0; kh < 4; ++kh) {
      half8 ahi[8], alo[8];
#pragma unroll
      for (int i = 0; i < 8; ++i) {
        int kf = kh * 8 + i;
        int byteoff = ((cn << 11) + kf * 64 + kg * 16) ^ ((cn & 7) << 4);
        ahi[i] = *reinterpret_cast<const half8*>(curh + byteoff);
        alo[i] = *reinterpret_cast<const half8*>(curl + byteoff);
      }
      // pass A: Whi fragments feed both hi and lo accumulators
#pragma unroll
      for (int i = 0; i < 8; ++i) {
#pragma unroll
        for (int nf = 0; nf < 8; ++nf) {
          half8 bfr = *reinterpret_cast<const half8*>(
              Whi + ((size_t)(n0w + nf * 16 + cn) << 10) + (kh * 8 + i) * 32 + kg * 8);
          acc1[nf] = __builtin_amdgcn_mfma_f32_16x16x32_f16(ahi[i], bfr, acc1[nf], 0, 0, 0);
          acc2[nf] = __builtin_amdgcn_mfma_f32_16x16x32_f16(alo[i], bfr, acc2[nf], 0, 0, 0);
        }
      }
      // pass B: Wlo fragments with hhi
#pragma unroll
      for (int i = 0; i < 8; ++i) {
#pragma unroll
        for (int nf = 0; nf < 8; ++nf) {
          half8 bfr = *reinterpret_cast<const half8*>(
              Wlo + ((size_t)(n0w + nf * 16 + cn) << 10) + (kh * 8 + i) * 32 + kg * 8);
          acc2[nf] = __builtin_amdgcn_mfma_f32_16x16x32_f16(ahi[i], bfr, acc2[nf], 0, 0, 0);
        }
      }
    }

    // epilogue: h = tanh(acc1 + acc2/S + xi + bh); split and write next buffer
    const int tglob = t0 + tt;
#pragma unroll
    for (int nf = 0; nf < 8; ++nf) {
      int n = n0w + nf * 16 + cn;
#pragma unroll
      for (int j = 0; j < 4; ++j) {
        int row = kg * 4 + j;
        int b   = r0 + row;
        float v = acc1[nf][j] + acc2[nf][j] * LOINV + bhv[nf] +
                  (float)xi[((size_t)(b * Tc + tt) << 10) + n];
        float h = tanhf(v);
        _Float16 hi = (_Float16)h;
        _Float16 lo = (_Float16)((h - (float)hi) * LOSCALE);
        int byteoff = ((row << 11) + (n << 1)) ^ ((row & 7) << 4);
        *reinterpret_cast<_Float16*>(nxth + byteoff) = hi;
        *reinterpret_cast<_Float16*>(nxtl + byteoff) = lo;
        if (tglob == SEQT - 1) out[((size_t)b << 10) + n] = h;
      }
    }
    __syncthreads();
  }

  // write back f32 h state from the buffer holding the latest h
#pragma unroll
  for (int i = 0; i < 4; ++i) {
    int idx = i * 512 + tid;
    int row = idx >> 7, c = idx & 127;
    int byteoff = ((row << 11) + (c << 4)) ^ ((row & 7) << 4);
    half8 vh = *reinterpret_cast<const half8*>(
        reinterpret_cast<const char*>(&Hhi[Tc & 1][0]) + byteoff);
    half8 vl = *reinterpret_cast<const half8*>(
        reinterpret_cast<const char*>(&Hlo[Tc & 1][0]) + byteoff);
    float* hp = hstate + ((size_t)(r0 + row) << 10) + c * 8;
#pragma unroll
    for (int j = 0; j < 8; ++j) hp[j] = (float)vh[j] + (float)vl[j] * LOINV;
  }
}

extern "C" void kernel_launch(void* const* d_in, const int* in_sizes, int n_in,
                              void* d_out, int out_size, void* d_ws, size_t ws_size,
                              hipStream_t stream) {
  const int*   x   = (const int*)  d_in[0];
  const float* emb = (const float*)d_in[1];
  const float* Wi  = (const float*)d_in[2];
  const float* bi  = (const float*)d_in[3];
  const float* Wh  = (const float*)d_in[4];
  const float* bh  = (const float*)d_in[5];
  float* out = (float*)d_out;

  char* ws = (char*)d_ws;
  size_t off = 0;
  auto alloc = [&](size_t bytes) -> void* {
    void* p = ws + off;
    off = (off + bytes + 255) & ~(size_t)255;
    return p;
  };

  _Float16* embh   = (_Float16*)alloc((size_t)VOCABN * EMBED * 2);
  _Float16* Wih    = (_Float16*)alloc((size_t)HID * EMBED * 2);
  _Float16* Whih   = (_Float16*)alloc((size_t)HID * HID * 2);
  _Float16* Wloh   = (_Float16*)alloc((size_t)HID * HID * 2);
  float*    hstate = (float*)   alloc((size_t)BATCHN * HID * 4);
  size_t fixed = off;

  // largest power-of-two T-chunk whose xi buffer fits in remaining ws
  int Tc = 1024;
  while (Tc > 4 && fixed + (size_t)BATCHN * Tc * HID * 2 > ws_size) Tc >>= 1;
  _Float16* xih = (_Float16*)alloc((size_t)BATCHN * Tc * HID * 2);

  {
    int n = VOCABN * EMBED;
    convert_f32_f16<<<n / 1024, 256, 0, stream>>>(emb, embh, n);
    n = HID * EMBED;
    convert_f32_f16<<<n / 1024, 256, 0, stream>>>(Wi, Wih, n);
    n = HID * HID;
    split_f32_f16<<<n / 1024, 256, 0, stream>>>(Wh, Whih, Wloh, n);
  }

  for (int t0 = 0; t0 < SEQT; t0 += Tc) {
    int M = BATCHN * Tc;
    int grid = (M / 128) * 8;  // 128x128 tiles over [M,1024]
    gemm_xi<<<grid, 256, 0, stream>>>(embh, Wih, x, bi, xih, t0, Tc);
    rnn_scan<<<16, 512, 0, stream>>>(Whih, Wloh, bh, xih, hstate, out, t0, Tc);
  }
}

// Round 3
// 16881.004 us; speedup vs baseline: 10.8027x; 10.8027x over previous
//
#include <hip/hip_runtime.h>
#include <cmath>

#define BATCHN 256
#define SEQT   1024
#define EMBED  1024
#define HID    1024
#define VOCABN 32000

typedef __attribute__((ext_vector_type(8))) _Float16 half8;
typedef __attribute__((ext_vector_type(4))) _Float16 half4;
typedef __attribute__((ext_vector_type(4))) float    float4v;
typedef __attribute__((ext_vector_type(4))) unsigned int uint4v;

#define LOSCALE 4096.0f
#define LOINV   (1.0f/4096.0f)

union FU16 { _Float16 f; unsigned short u; };
__device__ inline unsigned short f16bits(_Float16 f){ FU16 t; t.f=f; return t.u; }
__device__ inline _Float16 bits16(unsigned short u){ FU16 t; t.u=u; return t.f; }

__device__ inline void async16(const void* g, void* l) {
  __builtin_amdgcn_global_load_lds(
      (const __attribute__((address_space(1))) void*)g,
      (__attribute__((address_space(3))) void*)l, 16, 0, 0);
}

// ---------------- f32 -> f16 convert ----------------
__global__ void convert_f32_f16(const float* __restrict__ in,
                                _Float16* __restrict__ out, int n) {
  int i = (blockIdx.x * blockDim.x + threadIdx.x) * 4;
  if (i + 3 < n) {
    float4v v = *reinterpret_cast<const float4v*>(in + i);
    half4 o;
#pragma unroll
    for (int j = 0; j < 4; ++j) o[j] = (_Float16)v[j];
    *reinterpret_cast<half4*>(out + i) = o;
  }
}

// ---------------- f32 -> f16 hi/lo split (lo pre-scaled by 2^12) ----------------
__global__ void split_f32_f16(const float* __restrict__ in,
                              _Float16* __restrict__ hi,
                              _Float16* __restrict__ lo, int n) {
  int i = (blockIdx.x * blockDim.x + threadIdx.x) * 4;
  if (i + 3 < n) {
    float4v v = *reinterpret_cast<const float4v*>(in + i);
    half4 h, l;
#pragma unroll
    for (int j = 0; j < 4; ++j) {
      h[j] = (_Float16)v[j];
      l[j] = (_Float16)((v[j] - (float)h[j]) * LOSCALE);
    }
    *reinterpret_cast<half4*>(hi + i) = h;
    *reinterpret_cast<half4*>(lo + i) = l;
  }
}

// ---------------- Phase 1: xi = emb[x] @ Wi^T + bi  (f16 MFMA, 128x128 tile) ----------------
// xi layout: m = tt*256 + b (t-major within chunk), n inner.
__global__ __launch_bounds__(256, 2) void gemm_xi(
    const _Float16* __restrict__ embh,  // [VOCAB][1024] f16
    const _Float16* __restrict__ Wih,   // [1024][1024] f16 (n-major, k inner)
    const int* __restrict__ x,          // [256][1024]
    const float* __restrict__ bi,       // [1024]
    _Float16* __restrict__ xi,          // [Tc*256][1024] f16
    int t0, int Tc)
{
  __shared__ __align__(16) _Float16 As[128 * 64];
  __shared__ __align__(16) _Float16 Bs[128 * 64];
  __shared__ __align__(16) _Float16 stage[128 * 132];
  __shared__ int toks[128];

  const int tid  = threadIdx.x;
  const int wid  = tid >> 6, lane = tid & 63;
  const int nt   = blockIdx.x & 7, mt = blockIdx.x >> 3;
  const int m0   = mt * 128, n0 = nt * 128;

  if (tid < 128) {
    int m  = m0 + tid;
    int tl = m >> 8;           // local t within chunk
    int b  = m & 255;          // batch row
    toks[tid] = x[b * SEQT + t0 + tl];
  }
  __syncthreads();

  const _Float16* aptr[4];
  const _Float16* bptr[4];
  int ldsoff[4];
#pragma unroll
  for (int i = 0; i < 4; ++i) {
    int idx = i * 256 + tid;
    int row = idx >> 3, kc = idx & 7;
    aptr[i]   = embh + (size_t)toks[row] * 1024 + kc * 8;
    bptr[i]   = Wih + ((size_t)(n0 + row) << 10) + kc * 8;
    ldsoff[i] = idx * 8;  // elements
  }

  float4v acc[4][4] = {};
  const int wm = wid & 1, wn = wid >> 1;
  const int cn = lane & 15, kg = lane >> 4;

  for (int k0 = 0; k0 < 1024; k0 += 64) {
#pragma unroll
    for (int i = 0; i < 4; ++i) {
      async16(aptr[i] + k0, &As[ldsoff[i]]);
      async16(bptr[i] + k0, &Bs[ldsoff[i]]);
    }
    __syncthreads();

    half8 a[4][2], b[4][2];
#pragma unroll
    for (int mf = 0; mf < 4; ++mf)
#pragma unroll
      for (int kf = 0; kf < 2; ++kf)
        a[mf][kf] = *reinterpret_cast<const half8*>(
            &As[(wm * 64 + mf * 16 + cn) * 64 + kf * 32 + kg * 8]);
#pragma unroll
    for (int nf = 0; nf < 4; ++nf)
#pragma unroll
      for (int kf = 0; kf < 2; ++kf)
        b[nf][kf] = *reinterpret_cast<const half8*>(
            &Bs[(wn * 64 + nf * 16 + cn) * 64 + kf * 32 + kg * 8]);

#pragma unroll
    for (int mf = 0; mf < 4; ++mf)
#pragma unroll
      for (int nf = 0; nf < 4; ++nf)
#pragma unroll
        for (int kf = 0; kf < 2; ++kf)
          acc[mf][nf] = __builtin_amdgcn_mfma_f32_16x16x32_f16(
              a[mf][kf], b[nf][kf], acc[mf][nf], 0, 0, 0);
    __syncthreads();
  }

  // epilogue: add bi, stage in LDS, coalesced 16B stores
#pragma unroll
  for (int nf = 0; nf < 4; ++nf) {
    int n = wn * 64 + nf * 16 + cn;
    float biv = bi[n0 + n];
#pragma unroll
    for (int mf = 0; mf < 4; ++mf) {
#pragma unroll
      for (int j = 0; j < 4; ++j) {
        int m = wm * 64 + mf * 16 + kg * 4 + j;
        stage[m * 132 + n] = (_Float16)(acc[mf][nf][j] + biv);
      }
    }
  }
  __syncthreads();
#pragma unroll
  for (int p = 0; p < 8; ++p) {
    int chunk = p * 256 + tid;
    int r = chunk >> 4, cc = chunk & 15;
    half4 v0 = *reinterpret_cast<const half4*>(stage + r * 132 + cc * 8);
    half4 v1 = *reinterpret_cast<const half4*>(stage + r * 132 + cc * 8 + 4);
    half8 o;
#pragma unroll
    for (int e = 0; e < 4; ++e) { o[e] = v0[e]; o[4 + e] = v1[e]; }
    *reinterpret_cast<half8*>(xi + ((size_t)(m0 + r) << 10) + n0 + cc * 8) = o;
  }
}

// ---------------- Phase 2: persistent scan, 256 WGs = 16 batch-groups x 16 col-groups ----
// Each wave holds Whi+Wlo for its 16 cols in 256 VGPRs. h exchanged per step via
// packed-u32 global buffers (agent atomics / coherent loads) + per-group barrier.
__global__ __launch_bounds__(256, 1) void rnn_scan(
    const _Float16* __restrict__ Whig,  // [1024][1024] f16 (n-major)
    const _Float16* __restrict__ Wlog,  // [1024][1024] f16 residual * 2^12
    const float* __restrict__ bh,       // [1024]
    const _Float16* __restrict__ xi,    // [Tc*256][1024] f16 (t-major)
    float* __restrict__ hstate,         // [256][1024] f32
    float* __restrict__ out,            // [256][1024] f32
    unsigned int* __restrict__ hexA,    // [256][1024] u32 packed hi|lo<<16
    unsigned int* __restrict__ hexB,
    int* __restrict__ barc,             // [16*16] arrival counters
    int* __restrict__ barg,             // [16*16] generation counters
    int t0, int Tc)
{
  __shared__ __align__(16) _Float16 Ahi[16 * 1024];
  __shared__ __align__(16) _Float16 Alo[16 * 1024];

  const int tid  = threadIdx.x;
  const int wv   = tid >> 6, lane = tid & 63;
  const int cn   = lane & 15, kg = lane >> 4;
  const int gb   = blockIdx.x >> 4;     // batch group (16 rows)
  const int gc   = blockIdx.x & 15;     // col group (64 cols)
  const int r0   = gb * 16;
  const int wcol = gc * 64 + wv * 16 + cn;  // this lane's output column

  // ---- Wh resident in registers: 32 half8 hi + 32 half8 lo ----
  half8 whi[32], wlo[32];
  {
    const _Float16* wp = Whig + ((size_t)wcol << 10) + kg * 8;
    const _Float16* lp = Wlog + ((size_t)wcol << 10) + kg * 8;
#pragma unroll
    for (int kk = 0; kk < 32; ++kk) {
      whi[kk] = *reinterpret_cast<const half8*>(wp + kk * 32);
      wlo[kk] = *reinterpret_cast<const half8*>(lp + kk * 32);
    }
  }
  const float bhv = bh[wcol];

  // ---- init LDS h-tile (swizzle: byte ^= (row&7)<<4) ----
  if (t0 == 0) {
#pragma unroll
    for (int p = 0; p < 8; ++p) {
      int idx = p * 256 + tid, row = idx >> 7, cc = idx & 127;
      int bo = (((row << 11) + cc * 16) ^ ((row & 7) << 4));
      half8 z = {0, 0, 0, 0, 0, 0, 0, 0};
      *reinterpret_cast<half8*>(reinterpret_cast<char*>(Ahi) + bo) = z;
      *reinterpret_cast<half8*>(reinterpret_cast<char*>(Alo) + bo) = z;
    }
  } else {
#pragma unroll
    for (int p = 0; p < 8; ++p) {
      int idx = p * 256 + tid, row = idx >> 7, cc = idx & 127;
      const float* hp = hstate + (((size_t)(r0 + row)) << 10) + cc * 8;
      half8 vh, vl;
#pragma unroll
      for (int e = 0; e < 8; ++e) {
        float f = hp[e];
        _Float16 hi = (_Float16)f;
        vh[e] = hi;
        vl[e] = (_Float16)((f - (float)hi) * LOSCALE);
      }
      int bo = (((row << 11) + cc * 16) ^ ((row & 7) << 4));
      *reinterpret_cast<half8*>(reinterpret_cast<char*>(Ahi) + bo) = vh;
      *reinterpret_cast<half8*>(reinterpret_cast<char*>(Alo) + bo) = vl;
    }
  }
  __syncthreads();

  for (int tt = 0; tt < Tc; ++tt) {
    // prefetch xi (4 scalars; hidden under MFMA loop)
    unsigned short xiu[4];
#pragma unroll
    for (int j = 0; j < 4; ++j)
      xiu[j] = *reinterpret_cast<const unsigned short*>(
          xi + (((size_t)(tt * 256 + r0 + kg * 4 + j)) << 10) + wcol);

    // ---- 3-pass compensated matvec, 6 interleaved accumulators ----
    float4v a1a = {}, a1b = {}, a2a = {}, a2b = {}, a3a = {}, a3b = {};
#pragma unroll
    for (int kk = 0; kk < 32; ++kk) {
      int ab = (((cn << 11) + kk * 64 + kg * 16) ^ ((cn & 7) << 4));
      half8 ah = *reinterpret_cast<const half8*>(reinterpret_cast<const char*>(Ahi) + ab);
      half8 al = *reinterpret_cast<const half8*>(reinterpret_cast<const char*>(Alo) + ab);
      if (kk & 1) {
        a1b = __builtin_amdgcn_mfma_f32_16x16x32_f16(ah, whi[kk], a1b, 0, 0, 0);
        a2b = __builtin_amdgcn_mfma_f32_16x16x32_f16(al, whi[kk], a2b, 0, 0, 0);
        a3b = __builtin_amdgcn_mfma_f32_16x16x32_f16(ah, wlo[kk], a3b, 0, 0, 0);
      } else {
        a1a = __builtin_amdgcn_mfma_f32_16x16x32_f16(ah, whi[kk], a1a, 0, 0, 0);
        a2a = __builtin_amdgcn_mfma_f32_16x16x32_f16(al, whi[kk], a2a, 0, 0, 0);
        a3a = __builtin_amdgcn_mfma_f32_16x16x32_f16(ah, wlo[kk], a3a, 0, 0, 0);
      }
    }

    // ---- epilogue ----
    const int tglob = t0 + tt;
    unsigned int* hexW = ((tt + 1) & 1) ? hexA : hexB;
#pragma unroll
    for (int j = 0; j < 4; ++j) {
      int row = r0 + kg * 4 + j;
      float v = (a1a[j] + a1b[j]) +
                (a2a[j] + a2b[j] + a3a[j] + a3b[j]) * LOINV +
                bhv + (float)bits16(xiu[j]);
      float h = tanhf(v);
      if (tt < Tc - 1) {
        _Float16 hi = (_Float16)h;
        _Float16 lo = (_Float16)((h - (float)hi) * LOSCALE);
        unsigned int u = (unsigned int)f16bits(hi) | ((unsigned int)f16bits(lo) << 16);
        __hip_atomic_store(hexW + (((size_t)row) << 10) + wcol, u,
                           __ATOMIC_RELAXED, __HIP_MEMORY_SCOPE_AGENT);
      }
      if (tglob == SEQT - 1) out[(((size_t)row) << 10) + wcol] = h;
      else if (tt == Tc - 1) hstate[(((size_t)row) << 10) + wcol] = h;
    }
    if (tt == Tc - 1) break;  // no barrier/exchange after final step of chunk

    // ---- group barrier (16 WGs of this batch group) ----
    __syncthreads();   // drains all waves' stores (vmcnt 0 before s_barrier)
    if (tid == 0) {
      int old = __hip_atomic_fetch_add(barc + gb * 16, 1,
                                       __ATOMIC_ACQ_REL, __HIP_MEMORY_SCOPE_AGENT);
      if (old == 15) {
        __hip_atomic_store(barc + gb * 16, 0,
                           __ATOMIC_RELAXED, __HIP_MEMORY_SCOPE_AGENT);
        __hip_atomic_fetch_add(barg + gb * 16, 1,
                               __ATOMIC_RELEASE, __HIP_MEMORY_SCOPE_AGENT);
      } else {
        while (__hip_atomic_load(barg + gb * 16,
                                 __ATOMIC_ACQUIRE, __HIP_MEMORY_SCOPE_AGENT) < tt + 1)
          __builtin_amdgcn_s_sleep(2);
      }
    }
    __syncthreads();

    // ---- exchange: coherent-load full 16x1024 h, unpack to LDS ----
    const unsigned int* src = ((tt + 1) & 1) ? hexA : hexB;
    uint4v ta[8], tb[8];
#pragma unroll
    for (int p = 0; p < 8; ++p) {
      int idx = p * 256 + tid, row = idx >> 7, cc = idx & 127;
      unsigned long long ap =
          (unsigned long long)(src + (((size_t)(r0 + row)) << 10) + cc * 8);
      asm volatile("global_load_dwordx4 %0, %1, off sc0 sc1"
                   : "=v"(ta[p]) : "v"(ap) : "memory");
      asm volatile("global_load_dwordx4 %0, %1, off sc0 sc1"
                   : "=v"(tb[p]) : "v"(ap + 16) : "memory");
    }
    asm volatile("s_waitcnt vmcnt(0)" ::: "memory");
    __builtin_amdgcn_sched_barrier(0);
#pragma unroll
    for (int p = 0; p < 8; ++p) {
      int idx = p * 256 + tid, row = idx >> 7, cc = idx & 127;
      half8 vh, vl;
#pragma unroll
      for (int e = 0; e < 8; ++e) {
        unsigned int u = (e < 4) ? ta[p][e] : tb[p][e - 4];
        vh[e] = bits16((unsigned short)(u & 0xffffu));
        vl[e] = bits16((unsigned short)(u >> 16));
      }
      int bo = (((row << 11) + cc * 16) ^ ((row & 7) << 4));
      *reinterpret_cast<half8*>(reinterpret_cast<char*>(Ahi) + bo) = vh;
      *reinterpret_cast<half8*>(reinterpret_cast<char*>(Alo) + bo) = vl;
    }
    __syncthreads();
  }
}

extern "C" void kernel_launch(void* const* d_in, const int* in_sizes, int n_in,
                              void* d_out, int out_size, void* d_ws, size_t ws_size,
                              hipStream_t stream) {
  const int*   x   = (const int*)  d_in[0];
  const float* emb = (const float*)d_in[1];
  const float* Wi  = (const float*)d_in[2];
  const float* bi  = (const float*)d_in[3];
  const float* Wh  = (const float*)d_in[4];
  const float* bh  = (const float*)d_in[5];
  float* out = (float*)d_out;

  char* ws = (char*)d_ws;
  size_t off = 0;
  auto alloc = [&](size_t bytes) -> void* {
    void* p = ws + off;
    off = (off + bytes + 255) & ~(size_t)255;
    return p;
  };

  _Float16* embh   = (_Float16*)alloc((size_t)VOCABN * EMBED * 2);
  _Float16* Wih    = (_Float16*)alloc((size_t)HID * EMBED * 2);
  _Float16* Whih   = (_Float16*)alloc((size_t)HID * HID * 2);
  _Float16* Wloh   = (_Float16*)alloc((size_t)HID * HID * 2);
  float*    hstate = (float*)   alloc((size_t)BATCHN * HID * 4);
  unsigned int* hexA = (unsigned int*)alloc((size_t)BATCHN * HID * 4);
  unsigned int* hexB = (unsigned int*)alloc((size_t)BATCHN * HID * 4);
  int* barc = (int*)alloc(16 * 16 * 4);
  int* barg = (int*)alloc(16 * 16 * 4);
  size_t fixed = off;

  // largest power-of-two T-chunk whose xi buffer fits in remaining ws
  int Tc = 1024;
  while (Tc > 4 && fixed + (size_t)BATCHN * Tc * HID * 2 > ws_size) Tc >>= 1;
  _Float16* xih = (_Float16*)alloc((size_t)BATCHN * Tc * HID * 2);

  {
    int n = VOCABN * EMBED;
    convert_f32_f16<<<n / 1024, 256, 0, stream>>>(emb, embh, n);
    n = HID * EMBED;
    convert_f32_f16<<<n / 1024, 256, 0, stream>>>(Wi, Wih, n);
    n = HID * HID;
    split_f32_f16<<<n / 1024, 256, 0, stream>>>(Wh, Whih, Wloh, n);
  }

  for (int t0 = 0; t0 < SEQT; t0 += Tc) {
    int grid = (BATCHN * Tc / 128) * 8;  // 128x128 tiles over [256*Tc, 1024]
    gemm_xi<<<grid, 256, 0, stream>>>(embh, Wih, x, bi, xih, t0, Tc);
    hipMemsetAsync(barc, 0, 2 * 16 * 16 * 4, stream);  // barc+barg contiguous
    rnn_scan<<<256, 256, 0, stream>>>(Whih, Wloh, bh, xih, hstate, out,
                                      hexA, hexB, barc, barg, t0, Tc);
  }
}